// Round 9
// baseline (147.328 us; speedup 1.0000x reference)
//
#include <hip/hip_runtime.h>
#include <hip/hip_bf16.h>

typedef __attribute__((ext_vector_type(4))) float f32x4;
typedef __attribute__((ext_vector_type(2))) int   i32x2;
typedef __attribute__((ext_vector_type(4))) int   i32x4;
typedef __attribute__((ext_vector_type(8))) short short8;

__device__ __forceinline__ unsigned short f2bf(float x) {
  __hip_bfloat16 h = __float2bfloat16(x);
  union { __hip_bfloat16 h1; unsigned short u; } c; c.h1 = h; return c.u;
}
__device__ __forceinline__ unsigned pk2(float a, float b) {
  __hip_bfloat162 h = __float22bfloat162_rn(make_float2(a, b));
  union { __hip_bfloat162 h2; unsigned u; } c; c.h2 = h; return c.u;
}
__device__ __forceinline__ float bf2f(unsigned short u) {
  union { unsigned u32; float f; } c; c.u32 = ((unsigned)u) << 16; return c.f;
}

// ---------------------------------------------------------------------------
// Prep. grid 257 x 256:
//   blk<256 : row k=blk of W1u/W1v = edge_w@G1 -> bf16 fragment layout
//   blk==256: c1 = edge_b@G1 + gb0; zero the 32 batch counters
// ---------------------------------------------------------------------------
__global__ void k_prep(const float* __restrict__ edge_w, const float* __restrict__ edge_b,
                       const float* __restrict__ gw0, const float* __restrict__ gb0,
                       unsigned short* __restrict__ W1uR, unsigned short* __restrict__ W1vR,
                       float* __restrict__ c1, unsigned int* __restrict__ cnt) {
  const int blk = blockIdx.x, t = threadIdx.x;
  __shared__ float eu[256], ev[256];
  if (blk < 256) {
    eu[t] = edge_w[blk * 256 + t];
    ev[t] = edge_w[(256 + blk) * 256 + t];
    __syncthreads();
    float su = 0.f, sv = 0.f;
    for (int o = 0; o < 256; ++o) {
      float gg = gw0[o * 256 + t];
      su += eu[o] * gg; sv += ev[o] * gg;
    }
    const int k = blk, m = t;
    const int w = m >> 6, mf = (m >> 4) & 3, q = m & 15;
    const int ch = k >> 5, g = (k >> 3) & 3, e = k & 7;
    const int idx = ((w * 8 + ch) * 4 + mf) * 512 + (g * 16 + q) * 8 + e;
    W1uR[idx] = f2bf(su);
    W1vR[idx] = f2bf(sv);
  } else {
    float s = gb0[t];
    for (int o = 0; o < 256; ++o) s += edge_b[o] * gw0[o * 256 + t];
    c1[t] = s;
    if (t < 32) cnt[t] = 0u;
  }
}

// ---------------------------------------------------------------------------
// k_uv. grid 192 x 256:
//   blk<128 : U1(bf16)=x@W1u / V1c(f32)=x@W1v+c1 via MFMA (tile=blk>>1, sel=blk&1)
//   blk>=128: W2R/W3R = gw1/gw2 fragment-scheduled bf16 (no W1 dependency)
// ---------------------------------------------------------------------------
__global__ void k_uv(const float* __restrict__ x,
                     const unsigned short* __restrict__ W1uR,
                     const unsigned short* __restrict__ W1vR,
                     const float* __restrict__ c1,
                     const float* __restrict__ gw1, const float* __restrict__ gw2,
                     unsigned short* __restrict__ U1, float* __restrict__ V1c,
                     unsigned short* __restrict__ W2R, unsigned short* __restrict__ W3R) {
  __shared__ unsigned short xs[8192];       // [32 row][256 k] bf16, swizzled

  const int t = threadIdx.x;
  if (blockIdx.x >= 128) {
    int p = blockIdx.x - 128;                // 0..63: [0,32)->W2R, [32,64)->W3R
    const float* src = (p < 32) ? gw1 : gw2;
    unsigned short* dst = (p < 32) ? W2R : W3R;
    p &= 31;
    int w = p >> 3, ch = p & 7;
    int mf = t >> 6, lane = t & 63, q = lane & 15, g = lane >> 4;
    int base = ((w * 8 + ch) * 4 + mf) * 512 + lane * 8;
    int m = w * 64 + mf * 16 + q;
#pragma unroll
    for (int e = 0; e < 8; ++e) {
      int k = ch * 32 + g * 8 + e;
      dst[base + e] = f2bf(src[k * 256 + m]);
    }
    return;
  }

  const int tile = blockIdx.x >> 1, sel = blockIdx.x & 1;
  const int r0 = tile * 32;
  const int wid = t >> 6, lane = t & 63;
  const int q = lane & 15, g = lane >> 4;
  const int mo = wid << 6;

  {
    const int row = t >> 3, sl = t & 7, r7 = row & 7;
    const float* xB = x + (size_t)(r0 + row) * 256;
    unsigned short* hB = xs + row * 256;
#pragma unroll
    for (int m = 0; m < 4; ++m) {
      int ks = sl + 8 * m;
      f32x4 u0 = *(const f32x4*)(xB + ks * 8);
      f32x4 u1 = *(const f32x4*)(xB + ks * 8 + 4);
      i32x4 wv = { (int)pk2(u0.x, u0.y), (int)pk2(u0.z, u0.w),
                   (int)pk2(u1.x, u1.y), (int)pk2(u1.z, u1.w) };
      *(i32x4*)(hB + (ks ^ r7) * 8) = wv;
    }
  }

  const unsigned short* WR = sel ? W1vR : W1uR;
  const unsigned short* aW = WR + (size_t)wid * 16384 + lane * 8;

  short8 a_[4], an_[4];
#pragma unroll
  for (int mf = 0; mf < 4; ++mf) a_[mf] = *(const short8*)(aW + mf * 512);

  __syncthreads();

  f32x4 acc[4][2];
#pragma unroll
  for (int mf = 0; mf < 4; ++mf)
#pragma unroll
    for (int nf = 0; nf < 2; ++nf) acc[mf][nf] = (f32x4){0.f, 0.f, 0.f, 0.f};

  for (int ch = 0; ch < 8; ++ch) {
    if (ch < 7) {
#pragma unroll
      for (int mf = 0; mf < 4; ++mf)
        an_[mf] = *(const short8*)(aW + (ch + 1) * 2048 + mf * 512);
    }
    short8 b_[2];
#pragma unroll
    for (int nf = 0; nf < 2; ++nf) {
      int r = q + 16 * nf;
      b_[nf] = *(const short8*)(xs + r * 256 + (((ch * 4 + g) ^ (r & 7)) * 8));
    }
#pragma unroll
    for (int mf = 0; mf < 4; ++mf)
#pragma unroll
      for (int nf = 0; nf < 2; ++nf)
        acc[mf][nf] = __builtin_amdgcn_mfma_f32_16x16x32_bf16(a_[mf], b_[nf], acc[mf][nf], 0, 0, 0);
    if (ch < 7) {
#pragma unroll
      for (int mf = 0; mf < 4; ++mf) a_[mf] = an_[mf];
    }
  }

#pragma unroll
  for (int mf = 0; mf < 4; ++mf) {
    int c2b = mo + 16 * mf + 4 * g;
#pragma unroll
    for (int nf = 0; nf < 2; ++nf) {
      int r = r0 + q + 16 * nf;
      f32x4 v = acc[mf][nf];
      if (sel == 0) {
        i32x2 wv = { (int)pk2(v.x, v.y), (int)pk2(v.z, v.w) };
        *(i32x2*)(U1 + (size_t)r * 256 + c2b) = wv;
      } else {
        f32x4 cc = *(const f32x4*)(c1 + c2b);
        f32x4 o = { v.x + cc.x, v.y + cc.y, v.z + cc.z, v.w + cc.w };
        *(f32x4*)(V1c + (size_t)r * 256 + c2b) = o;
      }
    }
  }
}

// ---------------------------------------------------------------------------
// Main fused kernel — two itiles per block + fused f-MLP tail.
// grid 1024: block (b, ipair). LDS: bufA/bufB 32KB (h1 -> h2 -> f32 scratch).
// After partials: threadfence + atomicAdd(cnt[b]); 32nd block runs f-MLP for b.
// ---------------------------------------------------------------------------
__device__ __forceinline__ void write_h1(short8 u, f32x4 v0, f32x4 v1,
                                         unsigned short* dst) {
  float r0 = fmaxf(bf2f((unsigned short)u[0]) + v0.x, 0.f);
  float r1 = fmaxf(bf2f((unsigned short)u[1]) + v0.y, 0.f);
  float r2 = fmaxf(bf2f((unsigned short)u[2]) + v0.z, 0.f);
  float r3 = fmaxf(bf2f((unsigned short)u[3]) + v0.w, 0.f);
  float r4 = fmaxf(bf2f((unsigned short)u[4]) + v1.x, 0.f);
  float r5 = fmaxf(bf2f((unsigned short)u[5]) + v1.y, 0.f);
  float r6 = fmaxf(bf2f((unsigned short)u[6]) + v1.z, 0.f);
  float r7 = fmaxf(bf2f((unsigned short)u[7]) + v1.w, 0.f);
  i32x4 wv = { (int)pk2(r0, r1), (int)pk2(r2, r3), (int)pk2(r4, r5), (int)pk2(r6, r7) };
  *(i32x4*)dst = wv;
}

__launch_bounds__(256, 2)
__global__ void k_main(const unsigned short* __restrict__ U1,
                       const float* __restrict__ V1c,
                       const unsigned short* __restrict__ W2R,
                       const unsigned short* __restrict__ W3R,
                       const float* __restrict__ b2, const float* __restrict__ b3,
                       float* __restrict__ partials, unsigned int* __restrict__ cnt,
                       const float* __restrict__ f1w, const float* __restrict__ f1b,
                       const float* __restrict__ f2w, const float* __restrict__ f2b,
                       const float* __restrict__ f3w, const float* __restrict__ f3b,
                       float* __restrict__ out) {
  __shared__ unsigned short bufA[16384];   // 32KB, reused
  __shared__ unsigned short bufB[16384];   // 32KB, reused
  __shared__ int lastFlag;

  const int t = threadIdx.x;
  const int bid = blockIdx.x;
  const int wrk = ((bid & 7) << 7) | (bid >> 3);   // XCD swizzle (1024%8==0)
  const int b = wrk >> 5;
  const int it0 = (wrk & 31) * 2;
  const int wid = t >> 6, lane = t & 63;
  const int q = lane & 15, g = lane >> 4;
  const int mo = wid << 6;

  // ---- phase 0: stage h1_A / h1_B (shared U rows, two V rows) ----
  {
    const int row = t >> 2, sl = t & 3, r7 = row & 7;
    const unsigned short* uB = U1 + (size_t)(b * 64 + row) * 256;
    const float* vA = V1c + (size_t)(b * 64 + it0) * 256;
    const float* vB = vA + 256;
    unsigned short* dA = bufA + row * 256;
    unsigned short* dB = bufB + row * 256;
#pragma unroll
    for (int m = 0; m < 8; ++m) {
      int ks = sl + 4 * m;
      int s8 = (ks ^ r7) * 8;
      short8 u = *(const short8*)(uB + ks * 8);
      f32x4 a0 = *(const f32x4*)(vA + ks * 8);
      f32x4 a1 = *(const f32x4*)(vA + ks * 8 + 4);
      f32x4 b0 = *(const f32x4*)(vB + ks * 8);
      f32x4 b1 = *(const f32x4*)(vB + ks * 8 + 4);
      write_h1(u, a0, a1, dA + s8);
      write_h1(u, b0, b1, dB + s8);
    }
  }

  const unsigned short* aW2 = W2R + (size_t)wid * 16384 + lane * 8;
  const unsigned short* aW3 = W3R + (size_t)wid * 16384 + lane * 8;

  short8 a_[4], an_[4];
#pragma unroll
  for (int mf = 0; mf < 4; ++mf) a_[mf] = *(const short8*)(aW2 + mf * 512);

  __syncthreads();                         // [1] h1 complete

  f32x4 accA[4][4], accB[4][4];
#pragma unroll
  for (int mf = 0; mf < 4; ++mf)
#pragma unroll
    for (int nf = 0; nf < 4; ++nf) {
      accA[mf][nf] = (f32x4){0.f, 0.f, 0.f, 0.f};
      accB[mf][nf] = (f32x4){0.f, 0.f, 0.f, 0.f};
    }

  // ---- GEMM1: acc{A,B} = G2^T * h1{A,B}^T, 8 chunks, barrier-free ----
  for (int ch = 0; ch < 8; ++ch) {
    if (ch < 7) {
#pragma unroll
      for (int mf = 0; mf < 4; ++mf)
        an_[mf] = *(const short8*)(aW2 + (ch + 1) * 2048 + mf * 512);
    }
    short8 bA[4], bB[4];
#pragma unroll
    for (int nf = 0; nf < 4; ++nf) {
      int r = q + 16 * nf;
      int off = r * 256 + (((ch * 4 + g) ^ (r & 7)) * 8);
      bA[nf] = *(const short8*)(bufA + off);
      bB[nf] = *(const short8*)(bufB + off);
    }
#pragma unroll
    for (int mf = 0; mf < 4; ++mf)
#pragma unroll
      for (int nf = 0; nf < 4; ++nf) {
        accA[mf][nf] = __builtin_amdgcn_mfma_f32_16x16x32_bf16(a_[mf], bA[nf], accA[mf][nf], 0, 0, 0);
        accB[mf][nf] = __builtin_amdgcn_mfma_f32_16x16x32_bf16(a_[mf], bB[nf], accB[mf][nf], 0, 0, 0);
      }
    if (ch < 7) {
#pragma unroll
      for (int mf = 0; mf < 4; ++mf) a_[mf] = an_[mf];
    }
  }

  __syncthreads();                         // [2] all h1 reads done

  // ---- transition: h2{A,B} = relu(acc{A,B}+b2) -> buf{A,B}; prefetch W3 ----
#pragma unroll
  for (int mf = 0; mf < 4; ++mf) a_[mf] = *(const short8*)(aW3 + mf * 512);
#pragma unroll
  for (int mf = 0; mf < 4; ++mf) {
    int c2b = mo + 16 * mf + 4 * g;
    f32x4 bb = *(const f32x4*)(b2 + c2b);
    int ksw = c2b >> 3, off = c2b & 7;
#pragma unroll
    for (int nf = 0; nf < 4; ++nf) {
      int r = q + 16 * nf;
      int dst = r * 256 + ((ksw ^ (r & 7)) * 8) + off;
      f32x4 vA_ = accA[mf][nf];
      f32x4 vB_ = accB[mf][nf];
      i32x2 wA = { (int)pk2(fmaxf(vA_.x + bb.x, 0.f), fmaxf(vA_.y + bb.y, 0.f)),
                   (int)pk2(fmaxf(vA_.z + bb.z, 0.f), fmaxf(vA_.w + bb.w, 0.f)) };
      i32x2 wB = { (int)pk2(fmaxf(vB_.x + bb.x, 0.f), fmaxf(vB_.y + bb.y, 0.f)),
                   (int)pk2(fmaxf(vB_.z + bb.z, 0.f), fmaxf(vB_.w + bb.w, 0.f)) };
      *(i32x2*)(bufA + dst) = wA;
      *(i32x2*)(bufB + dst) = wB;
    }
  }
  __syncthreads();                         // [3] h2 complete

  // ---- GEMM2: reuse acc{A,B}, barrier-free ----
#pragma unroll
  for (int mf = 0; mf < 4; ++mf)
#pragma unroll
    for (int nf = 0; nf < 4; ++nf) {
      accA[mf][nf] = (f32x4){0.f, 0.f, 0.f, 0.f};
      accB[mf][nf] = (f32x4){0.f, 0.f, 0.f, 0.f};
    }

  for (int ch = 0; ch < 8; ++ch) {
    if (ch < 7) {
#pragma unroll
      for (int mf = 0; mf < 4; ++mf)
        an_[mf] = *(const short8*)(aW3 + (ch + 1) * 2048 + mf * 512);
    }
    short8 bA[4], bB[4];
#pragma unroll
    for (int nf = 0; nf < 4; ++nf) {
      int r = q + 16 * nf;
      int off = r * 256 + (((ch * 4 + g) ^ (r & 7)) * 8);
      bA[nf] = *(const short8*)(bufA + off);
      bB[nf] = *(const short8*)(bufB + off);
    }
#pragma unroll
    for (int mf = 0; mf < 4; ++mf)
#pragma unroll
      for (int nf = 0; nf < 4; ++nf) {
        accA[mf][nf] = __builtin_amdgcn_mfma_f32_16x16x32_bf16(a_[mf], bA[nf], accA[mf][nf], 0, 0, 0);
        accB[mf][nf] = __builtin_amdgcn_mfma_f32_16x16x32_bf16(a_[mf], bB[nf], accB[mf][nf], 0, 0, 0);
      }
    if (ch < 7) {
#pragma unroll
      for (int mf = 0; mf < 4; ++mf) a_[mf] = an_[mf];
    }
  }

  __syncthreads();                         // [4] all h2 reads done

  // ---- epilogue: h3 = relu(acc2+b3); row-sums via f32 LDS scratch ----
  float* scrA = (float*)&bufA[0];          // [16 q][264 pad] f32
  float* scrB = (float*)&bufB[0];
#pragma unroll
  for (int mf = 0; mf < 4; ++mf) {
    int n3b = mo + 16 * mf + 4 * g;
    f32x4 bb = *(const f32x4*)(b3 + n3b);
    f32x4 sA = (f32x4){0.f, 0.f, 0.f, 0.f};
    f32x4 sB = (f32x4){0.f, 0.f, 0.f, 0.f};
#pragma unroll
    for (int nf = 0; nf < 4; ++nf) {
      f32x4 vA_ = accA[mf][nf];
      f32x4 vB_ = accB[mf][nf];
      sA.x += fmaxf(vA_.x + bb.x, 0.f); sA.y += fmaxf(vA_.y + bb.y, 0.f);
      sA.z += fmaxf(vA_.z + bb.z, 0.f); sA.w += fmaxf(vA_.w + bb.w, 0.f);
      sB.x += fmaxf(vB_.x + bb.x, 0.f); sB.y += fmaxf(vB_.y + bb.y, 0.f);
      sB.z += fmaxf(vB_.z + bb.z, 0.f); sB.w += fmaxf(vB_.w + bb.w, 0.f);
    }
    *(f32x4*)(scrA + q * 264 + n3b) = sA;
    *(f32x4*)(scrB + q * 264 + n3b) = sB;
  }
  __syncthreads();                         // [5] scratch complete
  float sA = 0.f, sB = 0.f;
#pragma unroll
  for (int q2 = 0; q2 < 16; ++q2) {
    sA += scrA[q2 * 264 + t];
    sB += scrB[q2 * 264 + t];
  }
  partials[(size_t)(b * 64 + it0) * 256 + t] = sA;
  partials[(size_t)(b * 64 + it0 + 1) * 256 + t] = sB;

  // ---- fused f-MLP tail: 32nd completer for batch b does the f-MLP ----
  __threadfence();
  if (t == 0) lastFlag = (atomicAdd(&cnt[b], 1u) == 31u) ? 1 : 0;
  __syncthreads();                         // also guards bufA reuse below
  if (lastFlag) {
    __threadfence();
    float* xg = (float*)&bufA[0];
    float* x1 = xg + 256;
    float* x2 = xg + 512;
    {
      const float* p = partials + (size_t)(b * 64) * 256 + t;
      float s[8];
#pragma unroll
      for (int i = 0; i < 8; ++i) s[i] = 0.f;
#pragma unroll
      for (int k = 0; k < 8; ++k)
#pragma unroll
        for (int i = 0; i < 8; ++i) s[i] += p[(k * 8 + i) * 256];
      float tot = 0.f;
#pragma unroll
      for (int i = 0; i < 8; ++i) tot += s[i];
      xg[t] = tot;
    }
    __syncthreads();
    {
      float a0 = 0.f, a1 = 0.f, a2 = 0.f, a3 = 0.f;
#pragma unroll 4
      for (int k = 0; k < 64; ++k) {
        a0 += xg[k]       * f1w[(k)       * 256 + t];
        a1 += xg[k + 64]  * f1w[(k + 64)  * 256 + t];
        a2 += xg[k + 128] * f1w[(k + 128) * 256 + t];
        a3 += xg[k + 192] * f1w[(k + 192) * 256 + t];
      }
      x1[t] = fmaxf((a0 + a1) + (a2 + a3) + f1b[t], 0.f);
    }
    __syncthreads();
    {
      float a0 = 0.f, a1 = 0.f, a2 = 0.f, a3 = 0.f;
#pragma unroll 4
      for (int k = 0; k < 64; ++k) {
        a0 += x1[k]       * f2w[(k)       * 256 + t];
        a1 += x1[k + 64]  * f2w[(k + 64)  * 256 + t];
        a2 += x1[k + 128] * f2w[(k + 128) * 256 + t];
        a3 += x1[k + 192] * f2w[(k + 192) * 256 + t];
      }
      x2[t] = fmaxf((a0 + a1) + (a2 + a3) + f2b[t], 0.f);
    }
    __syncthreads();
    if (t < 128) {
      float a0 = 0.f, a1 = 0.f, a2 = 0.f, a3 = 0.f;
#pragma unroll 4
      for (int k = 0; k < 64; ++k) {
        a0 += x2[k]       * f3w[(k)       * 128 + t];
        a1 += x2[k + 64]  * f3w[(k + 64)  * 128 + t];
        a2 += x2[k + 128] * f3w[(k + 128) * 128 + t];
        a3 += x2[k + 192] * f3w[(k + 192) * 128 + t];
      }
      out[b * 128 + t] = (a0 + a1) + (a2 + a3) + f3b[t];
    }
  }
}

__global__ void k_zero(float* __restrict__ out, int n) {
  int i = blockIdx.x * 256 + threadIdx.x;
  if (i < n) out[i] = 0.f;
}

// ---------------------------------------------------------------------------
extern "C" void kernel_launch(void* const* d_in, const int* in_sizes, int n_in,
                              void* d_out, int out_size, void* d_ws, size_t ws_size,
                              hipStream_t stream) {
  const float* x      = (const float*)d_in[0];
  const float* edge_w = (const float*)d_in[1];
  const float* edge_b = (const float*)d_in[2];
  const float *gw0, *gw1, *gw2, *gb0, *gb1, *gb2;
  const float *f1w, *f1b, *f2w, *f2b, *f3w, *f3b;

  if (n_in >= 15 && in_sizes[3] == 65536 && in_sizes[4] == 65536 && in_sizes[5] == 65536) {
    gw0 = (const float*)d_in[3]; gw1 = (const float*)d_in[4]; gw2 = (const float*)d_in[5];
    gb0 = (const float*)d_in[6]; gb1 = (const float*)d_in[7]; gb2 = (const float*)d_in[8];
    f1w = (const float*)d_in[9];  f1b = (const float*)d_in[10];
    f2w = (const float*)d_in[11]; f2b = (const float*)d_in[12];
    f3w = (const float*)d_in[13]; f3b = (const float*)d_in[14];
  } else if (n_in >= 15 && in_sizes[3] == 65536 && in_sizes[4] == 256) {
    gw0 = (const float*)d_in[3]; gb0 = (const float*)d_in[4];
    gw1 = (const float*)d_in[5]; gb1 = (const float*)d_in[6];
    gw2 = (const float*)d_in[7]; gb2 = (const float*)d_in[8];
    f1w = (const float*)d_in[9];  f1b = (const float*)d_in[10];
    f2w = (const float*)d_in[11]; f2b = (const float*)d_in[12];
    f3w = (const float*)d_in[13]; f3b = (const float*)d_in[14];
  } else {
    const float* gws = (const float*)d_in[3];
    const float* gbs = (const float*)d_in[4];
    gw0 = gws;          gw1 = gws + 65536;  gw2 = gws + 131072;
    gb0 = gbs;          gb1 = gbs + 256;    gb2 = gbs + 512;
    f1w = (const float*)d_in[5];  f1b = (const float*)d_in[6];
    f2w = (const float*)d_in[7];  f2b = (const float*)d_in[8];
    f3w = (const float*)d_in[9];  f3b = (const float*)d_in[10];
  }

  char* ws = (char*)d_ws;
  float*          c1       = (float*)(ws);                     // 1KB
  unsigned short* W1uR     = (unsigned short*)(ws + 1024);     // 128KB
  unsigned short* W1vR     = (unsigned short*)(ws + 132096);   // 128KB
  unsigned short* W2R      = (unsigned short*)(ws + 263168);   // 128KB
  unsigned short* W3R      = (unsigned short*)(ws + 394240);   // 128KB
  unsigned short* U1       = (unsigned short*)(ws + 525312);   // 1MB (bf16)
  float*          V1c      = (float*)(ws + 1573888);           // 2MB
  float*          partials = (float*)(ws + 3671040);           // 2MB
  unsigned int*   cnt      = (unsigned int*)(ws + 5768192);    // 128B
  const size_t need = 5768320;
  (void)out_size; (void)n_in;

  if (ws_size < need) {
    k_zero<<<dim3((out_size + 255) / 256), dim3(256), 0, stream>>>((float*)d_out, out_size);
    return;
  }

  k_prep<<<dim3(257), dim3(256), 0, stream>>>(edge_w, edge_b, gw0, gb0,
                                              W1uR, W1vR, c1, cnt);
  k_uv<<<dim3(192), dim3(256), 0, stream>>>(x, W1uR, W1vR, c1, gw1, gw2,
                                            U1, V1c, W2R, W3R);
  k_main<<<dim3(1024), dim3(256), 0, stream>>>(U1, V1c, W2R, W3R, gb1, gb2,
                                               partials, cnt,
                                               f1w, f1b, f2w, f2b, f3w, f3b,
                                               (float*)d_out);
}

// Round 11
// 71.868 us; speedup vs baseline: 2.0500x; 2.0500x over previous
//
#include <hip/hip_runtime.h>
#include <hip/hip_bf16.h>

typedef __attribute__((ext_vector_type(4))) float f32x4;
typedef __attribute__((ext_vector_type(2))) int   i32x2;
typedef __attribute__((ext_vector_type(4))) int   i32x4;
typedef __attribute__((ext_vector_type(8))) short short8;

__device__ __forceinline__ unsigned short f2bf(float x) {
  __hip_bfloat16 h = __float2bfloat16(x);
  union { __hip_bfloat16 h1; unsigned short u; } c; c.h1 = h; return c.u;
}
__device__ __forceinline__ unsigned pk2(float a, float b) {
  __hip_bfloat162 h = __float22bfloat162_rn(make_float2(a, b));
  union { __hip_bfloat162 h2; unsigned u; } c; c.h2 = h; return c.u;
}
__device__ __forceinline__ float bf2f(unsigned short u) {
  union { unsigned u32; float f; } c; c.u32 = ((unsigned)u) << 16; return c.f;
}

// ---------------------------------------------------------------------------
// Prep. grid 321 x 256:
//   blk<256 : row k=blk of W1u/W1v = edge_w@G1, written DIRECTLY to the
//             bf16 fragment-scheduled layouts W1uR/W1vR.
//   blk==256: c1 = edge_b@G1 + gb0
//   blk 257..: W2R/W3R = gw1/gw2 fragment-scheduled bf16
//             (fragment (wave w, chunk ch, mf) = contiguous 1KB burst).
// ---------------------------------------------------------------------------
__global__ void k_prep(const float* __restrict__ edge_w, const float* __restrict__ edge_b,
                       const float* __restrict__ gw0, const float* __restrict__ gb0,
                       const float* __restrict__ gw1, const float* __restrict__ gw2,
                       unsigned short* __restrict__ W1uR, unsigned short* __restrict__ W1vR,
                       float* __restrict__ c1,
                       unsigned short* __restrict__ W2R, unsigned short* __restrict__ W3R) {
  const int blk = blockIdx.x, t = threadIdx.x;
  __shared__ float eu[256], ev[256];
  if (blk < 256) {
    eu[t] = edge_w[blk * 256 + t];
    ev[t] = edge_w[(256 + blk) * 256 + t];
    __syncthreads();
    float su = 0.f, sv = 0.f;
    for (int o = 0; o < 256; ++o) {
      float gg = gw0[o * 256 + t];
      su += eu[o] * gg; sv += ev[o] * gg;
    }
    // scatter (k=blk, m=t) into fragment layout
    const int k = blk, m = t;
    const int w = m >> 6, mf = (m >> 4) & 3, q = m & 15;
    const int ch = k >> 5, g = (k >> 3) & 3, e = k & 7;
    const int idx = ((w * 8 + ch) * 4 + mf) * 512 + (g * 16 + q) * 8 + e;
    W1uR[idx] = f2bf(su);
    W1vR[idx] = f2bf(sv);
  } else if (blk == 256) {
    float s = gb0[t];
    for (int o = 0; o < 256; ++o) s += edge_b[o] * gw0[o * 256 + t];
    c1[t] = s;
  } else {
    int p = blk - 257;                       // 0..63: [0,32)->W2R, [32,64)->W3R
    const float* src = (p < 32) ? gw1 : gw2;
    unsigned short* dst = (p < 32) ? W2R : W3R;
    p &= 31;
    int w = p >> 3, ch = p & 7;
    int mf = t >> 6, lane = t & 63, q = lane & 15, g = lane >> 4;
    int base = ((w * 8 + ch) * 4 + mf) * 512 + lane * 8;
    int m = w * 64 + mf * 16 + q;
#pragma unroll
    for (int e = 0; e < 8; ++e) {
      int k = ch * 32 + g * 8 + e;
      dst[base + e] = f2bf(src[k * 256 + m]);
    }
  }
}

// ---------------------------------------------------------------------------
// U1(bf16) = x @ W1u, V1c(f32) = x @ W1v + c1 — via MFMA.
// grid 128 x 256: tile = bid>>1 (32 rows), sel = bid&1 (0->U, 1->V).
// x staged bf16 into LDS (k_main swizzle family); W from fragment layout.
// ---------------------------------------------------------------------------
__global__ void k_uv(const float* __restrict__ x,
                     const unsigned short* __restrict__ W1uR,
                     const unsigned short* __restrict__ W1vR,
                     const float* __restrict__ c1,
                     unsigned short* __restrict__ U1, float* __restrict__ V1c) {
  __shared__ unsigned short xs[8192];       // [32 row][256 k] bf16, swizzled

  const int t = threadIdx.x;
  const int tile = blockIdx.x >> 1, sel = blockIdx.x & 1;
  const int r0 = tile * 32;
  const int wid = t >> 6, lane = t & 63;
  const int q = lane & 15, g = lane >> 4;
  const int mo = wid << 6;

  // stage x rows r0..r0+31 as bf16, element (r,k) at xs[r*256 + ((k>>3)^(r&7))*8 + (k&7)]
  {
    const int row = t >> 3, sl = t & 7, r7 = row & 7;
    const float* xB = x + (size_t)(r0 + row) * 256;
    unsigned short* hB = xs + row * 256;
#pragma unroll
    for (int m = 0; m < 4; ++m) {
      int ks = sl + 8 * m;
      f32x4 u0 = *(const f32x4*)(xB + ks * 8);
      f32x4 u1 = *(const f32x4*)(xB + ks * 8 + 4);
      i32x4 wv = { (int)pk2(u0.x, u0.y), (int)pk2(u0.z, u0.w),
                   (int)pk2(u1.x, u1.y), (int)pk2(u1.z, u1.w) };
      *(i32x4*)(hB + (ks ^ r7) * 8) = wv;
    }
  }

  const unsigned short* WR = sel ? W1vR : W1uR;
  const unsigned short* aW = WR + (size_t)wid * 16384 + lane * 8;

  short8 a_[4], an_[4];
#pragma unroll
  for (int mf = 0; mf < 4; ++mf) a_[mf] = *(const short8*)(aW + mf * 512);

  __syncthreads();

  f32x4 acc[4][2];
#pragma unroll
  for (int mf = 0; mf < 4; ++mf)
#pragma unroll
    for (int nf = 0; nf < 2; ++nf) acc[mf][nf] = (f32x4){0.f, 0.f, 0.f, 0.f};

  for (int ch = 0; ch < 8; ++ch) {
    if (ch < 7) {
#pragma unroll
      for (int mf = 0; mf < 4; ++mf)
        an_[mf] = *(const short8*)(aW + (ch + 1) * 2048 + mf * 512);
    }
    short8 b_[2];
#pragma unroll
    for (int nf = 0; nf < 2; ++nf) {
      int r = q + 16 * nf;
      b_[nf] = *(const short8*)(xs + r * 256 + (((ch * 4 + g) ^ (r & 7)) * 8));
    }
#pragma unroll
    for (int mf = 0; mf < 4; ++mf)
#pragma unroll
      for (int nf = 0; nf < 2; ++nf)
        acc[mf][nf] = __builtin_amdgcn_mfma_f32_16x16x32_bf16(a_[mf], b_[nf], acc[mf][nf], 0, 0, 0);
    if (ch < 7) {
#pragma unroll
      for (int mf = 0; mf < 4; ++mf) a_[mf] = an_[mf];
    }
  }

  // epilogue: C[feat][row] frag -> row-major outputs
#pragma unroll
  for (int mf = 0; mf < 4; ++mf) {
    int c2b = mo + 16 * mf + 4 * g;          // 4 consecutive features
#pragma unroll
    for (int nf = 0; nf < 2; ++nf) {
      int r = r0 + q + 16 * nf;
      f32x4 v = acc[mf][nf];
      if (sel == 0) {
        i32x2 wv = { (int)pk2(v.x, v.y), (int)pk2(v.z, v.w) };
        *(i32x2*)(U1 + (size_t)r * 256 + c2b) = wv;
      } else {
        f32x4 cc = *(const f32x4*)(c1 + c2b);
        f32x4 o = { v.x + cc.x, v.y + cc.y, v.z + cc.z, v.w + cc.w };
        *(f32x4*)(V1c + (size_t)r * 256 + c2b) = o;
      }
    }
  }
}

// ---------------------------------------------------------------------------
// Main fused kernel — TWO itiles per block (halves W L2 traffic).
// grid 1024: block (b, ipair) -> itiles {2*ipair, 2*ipair+1}, 64 pair-rows each.
// LDS: bufA/bufB 32KB each (h1 -> h2 -> f32 scratch). 2 blocks/CU.
// Per chunk: 4 W-frag loads + 8 ds_reads feed 32 MFMA.
// ---------------------------------------------------------------------------
__device__ __forceinline__ void write_h1(short8 u, f32x4 v0, f32x4 v1,
                                         unsigned short* dst) {
  float r0 = fmaxf(bf2f((unsigned short)u[0]) + v0.x, 0.f);
  float r1 = fmaxf(bf2f((unsigned short)u[1]) + v0.y, 0.f);
  float r2 = fmaxf(bf2f((unsigned short)u[2]) + v0.z, 0.f);
  float r3 = fmaxf(bf2f((unsigned short)u[3]) + v0.w, 0.f);
  float r4 = fmaxf(bf2f((unsigned short)u[4]) + v1.x, 0.f);
  float r5 = fmaxf(bf2f((unsigned short)u[5]) + v1.y, 0.f);
  float r6 = fmaxf(bf2f((unsigned short)u[6]) + v1.z, 0.f);
  float r7 = fmaxf(bf2f((unsigned short)u[7]) + v1.w, 0.f);
  i32x4 wv = { (int)pk2(r0, r1), (int)pk2(r2, r3), (int)pk2(r4, r5), (int)pk2(r6, r7) };
  *(i32x4*)dst = wv;
}

__launch_bounds__(256, 2)
__global__ void k_main(const unsigned short* __restrict__ U1,
                       const float* __restrict__ V1c,
                       const unsigned short* __restrict__ W2R,
                       const unsigned short* __restrict__ W3R,
                       const float* __restrict__ b2, const float* __restrict__ b3,
                       float* __restrict__ partials) {
  __shared__ unsigned short bufA[16384];   // 32KB, reused
  __shared__ unsigned short bufB[16384];   // 32KB, reused

  const int t = threadIdx.x;
  const int bid = blockIdx.x;
  const int wrk = ((bid & 7) << 7) | (bid >> 3);   // XCD swizzle (1024%8==0)
  const int b = wrk >> 5;
  const int it0 = (wrk & 31) * 2;
  const int wid = t >> 6, lane = t & 63;
  const int q = lane & 15, g = lane >> 4;
  const int mo = wid << 6;

  // ---- phase 0: stage h1_A / h1_B (shared U rows, two V rows) ----
  {
    const int row = t >> 2, sl = t & 3, r7 = row & 7;
    const unsigned short* uB = U1 + (size_t)(b * 64 + row) * 256;
    const float* vA = V1c + (size_t)(b * 64 + it0) * 256;
    const float* vB = vA + 256;
    unsigned short* dA = bufA + row * 256;
    unsigned short* dB = bufB + row * 256;
#pragma unroll
    for (int m = 0; m < 8; ++m) {
      int ks = sl + 4 * m;
      int s8 = (ks ^ r7) * 8;
      short8 u = *(const short8*)(uB + ks * 8);
      f32x4 a0 = *(const f32x4*)(vA + ks * 8);
      f32x4 a1 = *(const f32x4*)(vA + ks * 8 + 4);
      f32x4 b0 = *(const f32x4*)(vB + ks * 8);
      f32x4 b1 = *(const f32x4*)(vB + ks * 8 + 4);
      write_h1(u, a0, a1, dA + s8);
      write_h1(u, b0, b1, dB + s8);
    }
  }

  const unsigned short* aW2 = W2R + (size_t)wid * 16384 + lane * 8;
  const unsigned short* aW3 = W3R + (size_t)wid * 16384 + lane * 8;

  short8 a_[4], an_[4];
#pragma unroll
  for (int mf = 0; mf < 4; ++mf) a_[mf] = *(const short8*)(aW2 + mf * 512);

  __syncthreads();                         // [1] h1 complete

  f32x4 accA[4][4], accB[4][4];
#pragma unroll
  for (int mf = 0; mf < 4; ++mf)
#pragma unroll
    for (int nf = 0; nf < 4; ++nf) {
      accA[mf][nf] = (f32x4){0.f, 0.f, 0.f, 0.f};
      accB[mf][nf] = (f32x4){0.f, 0.f, 0.f, 0.f};
    }

  // ---- GEMM1: acc{A,B} = G2^T * h1{A,B}^T, 8 chunks, barrier-free ----
  for (int ch = 0; ch < 8; ++ch) {
    if (ch < 7) {
#pragma unroll
      for (int mf = 0; mf < 4; ++mf)
        an_[mf] = *(const short8*)(aW2 + (ch + 1) * 2048 + mf * 512);
    }
    short8 bA[4], bB[4];
#pragma unroll
    for (int nf = 0; nf < 4; ++nf) {
      int r = q + 16 * nf;
      int off = r * 256 + (((ch * 4 + g) ^ (r & 7)) * 8);
      bA[nf] = *(const short8*)(bufA + off);
      bB[nf] = *(const short8*)(bufB + off);
    }
#pragma unroll
    for (int mf = 0; mf < 4; ++mf)
#pragma unroll
      for (int nf = 0; nf < 4; ++nf) {
        accA[mf][nf] = __builtin_amdgcn_mfma_f32_16x16x32_bf16(a_[mf], bA[nf], accA[mf][nf], 0, 0, 0);
        accB[mf][nf] = __builtin_amdgcn_mfma_f32_16x16x32_bf16(a_[mf], bB[nf], accB[mf][nf], 0, 0, 0);
      }
    if (ch < 7) {
#pragma unroll
      for (int mf = 0; mf < 4; ++mf) a_[mf] = an_[mf];
    }
  }

  __syncthreads();                         // [2] all h1 reads done

  // ---- transition: h2{A,B} = relu(acc{A,B}+b2) -> buf{A,B}; prefetch W3 ----
#pragma unroll
  for (int mf = 0; mf < 4; ++mf) a_[mf] = *(const short8*)(aW3 + mf * 512);
#pragma unroll
  for (int mf = 0; mf < 4; ++mf) {
    int c2b = mo + 16 * mf + 4 * g;
    f32x4 bb = *(const f32x4*)(b2 + c2b);
    int ksw = c2b >> 3, off = c2b & 7;
#pragma unroll
    for (int nf = 0; nf < 4; ++nf) {
      int r = q + 16 * nf;
      int dst = r * 256 + ((ksw ^ (r & 7)) * 8) + off;
      f32x4 vA_ = accA[mf][nf];
      f32x4 vB_ = accB[mf][nf];
      i32x2 wA = { (int)pk2(fmaxf(vA_.x + bb.x, 0.f), fmaxf(vA_.y + bb.y, 0.f)),
                   (int)pk2(fmaxf(vA_.z + bb.z, 0.f), fmaxf(vA_.w + bb.w, 0.f)) };
      i32x2 wB = { (int)pk2(fmaxf(vB_.x + bb.x, 0.f), fmaxf(vB_.y + bb.y, 0.f)),
                   (int)pk2(fmaxf(vB_.z + bb.z, 0.f), fmaxf(vB_.w + bb.w, 0.f)) };
      *(i32x2*)(bufA + dst) = wA;
      *(i32x2*)(bufB + dst) = wB;
    }
  }
  __syncthreads();                         // [3] h2 complete

  // ---- GEMM2: reuse acc{A,B}, barrier-free ----
#pragma unroll
  for (int mf = 0; mf < 4; ++mf)
#pragma unroll
    for (int nf = 0; nf < 4; ++nf) {
      accA[mf][nf] = (f32x4){0.f, 0.f, 0.f, 0.f};
      accB[mf][nf] = (f32x4){0.f, 0.f, 0.f, 0.f};
    }

  for (int ch = 0; ch < 8; ++ch) {
    if (ch < 7) {
#pragma unroll
      for (int mf = 0; mf < 4; ++mf)
        an_[mf] = *(const short8*)(aW3 + (ch + 1) * 2048 + mf * 512);
    }
    short8 bA[4], bB[4];
#pragma unroll
    for (int nf = 0; nf < 4; ++nf) {
      int r = q + 16 * nf;
      int off = r * 256 + (((ch * 4 + g) ^ (r & 7)) * 8);
      bA[nf] = *(const short8*)(bufA + off);
      bB[nf] = *(const short8*)(bufB + off);
    }
#pragma unroll
    for (int mf = 0; mf < 4; ++mf)
#pragma unroll
      for (int nf = 0; nf < 4; ++nf) {
        accA[mf][nf] = __builtin_amdgcn_mfma_f32_16x16x32_bf16(a_[mf], bA[nf], accA[mf][nf], 0, 0, 0);
        accB[mf][nf] = __builtin_amdgcn_mfma_f32_16x16x32_bf16(a_[mf], bB[nf], accB[mf][nf], 0, 0, 0);
      }
    if (ch < 7) {
#pragma unroll
      for (int mf = 0; mf < 4; ++mf) a_[mf] = an_[mf];
    }
  }

  __syncthreads();                         // [4] all h2 reads done

  // ---- epilogue: h3 = relu(acc2+b3); row-sums via f32 LDS scratch ----
  float* scrA = (float*)&bufA[0];          // [16 q][264 pad] f32
  float* scrB = (float*)&bufB[0];
#pragma unroll
  for (int mf = 0; mf < 4; ++mf) {
    int n3b = mo + 16 * mf + 4 * g;
    f32x4 bb = *(const f32x4*)(b3 + n3b);
    f32x4 sA = (f32x4){0.f, 0.f, 0.f, 0.f};
    f32x4 sB = (f32x4){0.f, 0.f, 0.f, 0.f};
#pragma unroll
    for (int nf = 0; nf < 4; ++nf) {
      f32x4 vA_ = accA[mf][nf];
      f32x4 vB_ = accB[mf][nf];
      sA.x += fmaxf(vA_.x + bb.x, 0.f); sA.y += fmaxf(vA_.y + bb.y, 0.f);
      sA.z += fmaxf(vA_.z + bb.z, 0.f); sA.w += fmaxf(vA_.w + bb.w, 0.f);
      sB.x += fmaxf(vB_.x + bb.x, 0.f); sB.y += fmaxf(vB_.y + bb.y, 0.f);
      sB.z += fmaxf(vB_.z + bb.z, 0.f); sB.w += fmaxf(vB_.w + bb.w, 0.f);
    }
    *(f32x4*)(scrA + q * 264 + n3b) = sA;
    *(f32x4*)(scrB + q * 264 + n3b) = sB;
  }
  __syncthreads();                         // [5] scratch complete
  float sA = 0.f, sB = 0.f;
#pragma unroll
  for (int q2 = 0; q2 < 16; ++q2) {
    sA += scrA[q2 * 264 + t];
    sB += scrB[q2 * 264 + t];
  }
  partials[(size_t)(b * 64 + it0) * 256 + t] = sA;
  partials[(size_t)(b * 64 + it0 + 1) * 256 + t] = sB;
}

// ---------------------------------------------------------------------------
// Reduce partials per batch + f-MLP (f32). grid 32 x 256.
// ---------------------------------------------------------------------------
__global__ void k_fmlp(const float* __restrict__ partials,
                       const float* __restrict__ f1w, const float* __restrict__ f1b,
                       const float* __restrict__ f2w, const float* __restrict__ f2b,
                       const float* __restrict__ f3w, const float* __restrict__ f3b,
                       float* __restrict__ out) {
  const int b = blockIdx.x, t = threadIdx.x;
  __shared__ float xg[256], x1[256], x2[256];
  {
    const float* p = partials + (size_t)(b * 64) * 256 + t;
    float s[8];
#pragma unroll
    for (int i = 0; i < 8; ++i) s[i] = 0.f;
#pragma unroll
    for (int k = 0; k < 8; ++k)
#pragma unroll
      for (int i = 0; i < 8; ++i) s[i] += p[(k * 8 + i) * 256];
    float tot = 0.f;
#pragma unroll
    for (int i = 0; i < 8; ++i) tot += s[i];
    xg[t] = tot;
  }
  __syncthreads();
  {
    float a0 = 0.f, a1 = 0.f, a2 = 0.f, a3 = 0.f;
#pragma unroll 4
    for (int k = 0; k < 64; ++k) {
      a0 += xg[k]       * f1w[(k)       * 256 + t];
      a1 += xg[k + 64]  * f1w[(k + 64)  * 256 + t];
      a2 += xg[k + 128] * f1w[(k + 128) * 256 + t];
      a3 += xg[k + 192] * f1w[(k + 192) * 256 + t];
    }
    x1[t] = fmaxf((a0 + a1) + (a2 + a3) + f1b[t], 0.f);
  }
  __syncthreads();
  {
    float a0 = 0.f, a1 = 0.f, a2 = 0.f, a3 = 0.f;
#pragma unroll 4
    for (int k = 0; k < 64; ++k) {
      a0 += x1[k]       * f2w[(k)       * 256 + t];
      a1 += x1[k + 64]  * f2w[(k + 64)  * 256 + t];
      a2 += x1[k + 128] * f2w[(k + 128) * 256 + t];
      a3 += x1[k + 192] * f2w[(k + 192) * 256 + t];
    }
    x2[t] = fmaxf((a0 + a1) + (a2 + a3) + f2b[t], 0.f);
  }
  __syncthreads();
  if (t < 128) {
    float a0 = 0.f, a1 = 0.f, a2 = 0.f, a3 = 0.f;
#pragma unroll 4
    for (int k = 0; k < 64; ++k) {
      a0 += x2[k]       * f3w[(k)       * 128 + t];
      a1 += x2[k + 64]  * f3w[(k + 64)  * 128 + t];
      a2 += x2[k + 128] * f3w[(k + 128) * 128 + t];
      a3 += x2[k + 192] * f3w[(k + 192) * 128 + t];
    }
    out[b * 128 + t] = (a0 + a1) + (a2 + a3) + f3b[t];
  }
}

__global__ void k_zero(float* __restrict__ out, int n) {
  int i = blockIdx.x * 256 + threadIdx.x;
  if (i < n) out[i] = 0.f;
}

// ---------------------------------------------------------------------------
extern "C" void kernel_launch(void* const* d_in, const int* in_sizes, int n_in,
                              void* d_out, int out_size, void* d_ws, size_t ws_size,
                              hipStream_t stream) {
  const float* x      = (const float*)d_in[0];
  const float* edge_w = (const float*)d_in[1];
  const float* edge_b = (const float*)d_in[2];
  const float *gw0, *gw1, *gw2, *gb0, *gb1, *gb2;
  const float *f1w, *f1b, *f2w, *f2b, *f3w, *f3b;

  if (n_in >= 15 && in_sizes[3] == 65536 && in_sizes[4] == 65536 && in_sizes[5] == 65536) {
    gw0 = (const float*)d_in[3]; gw1 = (const float*)d_in[4]; gw2 = (const float*)d_in[5];
    gb0 = (const float*)d_in[6]; gb1 = (const float*)d_in[7]; gb2 = (const float*)d_in[8];
    f1w = (const float*)d_in[9];  f1b = (const float*)d_in[10];
    f2w = (const float*)d_in[11]; f2b = (const float*)d_in[12];
    f3w = (const float*)d_in[13]; f3b = (const float*)d_in[14];
  } else if (n_in >= 15 && in_sizes[3] == 65536 && in_sizes[4] == 256) {
    gw0 = (const float*)d_in[3]; gb0 = (const float*)d_in[4];
    gw1 = (const float*)d_in[5]; gb1 = (const float*)d_in[6];
    gw2 = (const float*)d_in[7]; gb2 = (const float*)d_in[8];
    f1w = (const float*)d_in[9];  f1b = (const float*)d_in[10];
    f2w = (const float*)d_in[11]; f2b = (const float*)d_in[12];
    f3w = (const float*)d_in[13]; f3b = (const float*)d_in[14];
  } else {
    const float* gws = (const float*)d_in[3];
    const float* gbs = (const float*)d_in[4];
    gw0 = gws;          gw1 = gws + 65536;  gw2 = gws + 131072;
    gb0 = gbs;          gb1 = gbs + 256;    gb2 = gbs + 512;
    f1w = (const float*)d_in[5];  f1b = (const float*)d_in[6];
    f2w = (const float*)d_in[7];  f2b = (const float*)d_in[8];
    f3w = (const float*)d_in[9];  f3b = (const float*)d_in[10];
  }

  char* ws = (char*)d_ws;
  float*          c1       = (float*)(ws);                     // 1KB
  unsigned short* W1uR     = (unsigned short*)(ws + 1024);     // 128KB
  unsigned short* W1vR     = (unsigned short*)(ws + 132096);   // 128KB
  unsigned short* W2R      = (unsigned short*)(ws + 263168);   // 128KB
  unsigned short* W3R      = (unsigned short*)(ws + 394240);   // 128KB
  unsigned short* U1       = (unsigned short*)(ws + 525312);   // 1MB (bf16)
  float*          V1c      = (float*)(ws + 1573888);           // 2MB
  float*          partials = (float*)(ws + 3671040);           // 2MB
  const size_t need = 5768192;
  (void)out_size; (void)n_in;

  if (ws_size < need) {
    k_zero<<<dim3((out_size + 255) / 256), dim3(256), 0, stream>>>((float*)d_out, out_size);
    return;
  }

  k_prep<<<dim3(321), dim3(256), 0, stream>>>(edge_w, edge_b, gw0, gb0, gw1, gw2,
                                              W1uR, W1vR, c1, W2R, W3R);
  k_uv<<<dim3(128), dim3(256), 0, stream>>>(x, W1uR, W1vR, c1, U1, V1c);
  k_main<<<dim3(1024), dim3(256), 0, stream>>>(U1, V1c, W2R, W3R, gb1, gb2,
                                               partials);
  k_fmlp<<<dim3(32), dim3(256), 0, stream>>>(partials, f1w, f1b, f2w, f2b, f3w, f3b,
                                             (float*)d_out);
}